// Round 1
// baseline (2128.092 us; speedup 1.0000x reference)
//
#include <hip/hip_runtime.h>

#define NN 100000
#define NE 1600000
#define NG 256

// ---------------------------------------------------------------------------
// Workspace layout (floats):
//   norm_out : [0, NN)
//   norm_in  : [NN, 2NN)
//   counts   : [2NN, 2NN+256)        (later holds 1/max(count,1))
//   agg      : [2NN+256, +32NN)      (reused per layer, zeroed each time)
//   buf      : [.., +64NN)           (xs0 -> xs1 -> xs2 -> p, reused)
// total = 98*NN + 256 floats ~= 39.2 MB
// ---------------------------------------------------------------------------

__global__ void k_degree(const int* __restrict__ src, const int* __restrict__ dst,
                         float* __restrict__ deg_out, float* __restrict__ deg_in) {
  int i = blockIdx.x * blockDim.x + threadIdx.x;
  if (i < NE) {
    atomicAdd(&deg_out[src[i]], 1.0f);
    atomicAdd(&deg_in[dst[i]], 1.0f);
  }
}

// deg -> norm (in place), scale n_feat by norm_out into xs, histogram graphs
__global__ void k_norm_scale(const float* __restrict__ n_feat, const int* __restrict__ gid,
                             float* __restrict__ norm_out, float* __restrict__ norm_in,
                             float* __restrict__ counts, float* __restrict__ xs) {
  int i = blockIdx.x * blockDim.x + threadIdx.x;
  if (i >= NN) return;
  float d_o = norm_out[i];
  float no = d_o > 0.f ? 1.0f / sqrtf(d_o) : 0.0f;
  norm_out[i] = no;
  float d_i = norm_in[i];
  norm_in[i] = d_i > 0.f ? 1.0f / sqrtf(d_i) : 0.0f;
  float4 a = *reinterpret_cast<const float4*>(n_feat + (size_t)i * 8);
  float4 b = *reinterpret_cast<const float4*>(n_feat + (size_t)i * 8 + 4);
  a.x *= no; a.y *= no; a.z *= no; a.w *= no;
  b.x *= no; b.y *= no; b.z *= no; b.w *= no;
  *reinterpret_cast<float4*>(xs + (size_t)i * 8) = a;
  *reinterpret_cast<float4*>(xs + (size_t)i * 8 + 4) = b;
  atomicAdd(&counts[gid[i]], 1.0f);
}

__global__ void k_invcounts(float* __restrict__ counts) {
  int g = threadIdx.x;
  if (g < NG) counts[g] = 1.0f / fmaxf(counts[g], 1.0f);
}

// scatter: agg[dst] += xs[src], D floats per edge, one thread per (edge, float4)
template <int D>
__global__ void k_scatter(const float* __restrict__ xs, const int* __restrict__ src,
                          const int* __restrict__ dst, float* __restrict__ agg) {
  constexpr int C = D / 4;
  int t = blockIdx.x * blockDim.x + threadIdx.x;
  if (t >= NE * C) return;
  int e = t / C;
  int c = t % C;
  int s = src[e], d = dst[e];
  float4 v = *reinterpret_cast<const float4*>(xs + (size_t)s * D + c * 4);
  float* a = agg + (size_t)d * D + c * 4;
  atomicAdd(a + 0, v.x);
  atomicAdd(a + 1, v.y);
  atomicAdd(a + 2, v.z);
  atomicAdd(a + 3, v.w);
}

// node update: xs_out = relu((agg*norm_in) @ W + b) * norm_out   (layers 1,2)
template <int DIN, int DOUT>
__global__ void k_layer(const float* __restrict__ agg, const float* __restrict__ norm_in,
                        const float* __restrict__ norm_out,
                        const float* __restrict__ W, const float* __restrict__ b,
                        float* __restrict__ xs_out) {
  int i = blockIdx.x * blockDim.x + threadIdx.x;
  if (i >= NN) return;
  float ni = norm_in[i];
  float x[DIN];
#pragma unroll
  for (int k = 0; k < DIN; ++k) x[k] = agg[(size_t)i * DIN + k] * ni;
  float no = norm_out[i];
#pragma unroll
  for (int j = 0; j < DOUT; ++j) {
    float acc = b[j];
#pragma unroll
    for (int k = 0; k < DIN; ++k) acc = fmaf(x[k], W[k * DOUT + j], acc);
    acc = fmaxf(acc, 0.f);  // relu
    xs_out[(size_t)i * DOUT + j] = acc * no;
  }
}

// layer3 (32->128, no relu) fused with maxpool(2) -> p [N,64]
__global__ void k_tail_a(const float* __restrict__ agg, const float* __restrict__ norm_in,
                         const float* __restrict__ W3, const float* __restrict__ b3,
                         float* __restrict__ p_out) {
  int i = blockIdx.x * blockDim.x + threadIdx.x;
  if (i >= NN) return;
  float ni = norm_in[i];
  float x[32];
#pragma unroll
  for (int k = 0; k < 32; ++k) x[k] = agg[(size_t)i * 32 + k] * ni;
#pragma unroll
  for (int j = 0; j < 64; ++j) {
    float a0 = b3[2 * j], a1 = b3[2 * j + 1];
#pragma unroll
    for (int k = 0; k < 32; ++k) {
      a0 = fmaf(x[k], W3[k * 128 + 2 * j], a0);
      a1 = fmaf(x[k], W3[k * 128 + 2 * j + 1], a1);
    }
    p_out[(size_t)i * 64 + j] = fmaxf(a0, a1);
  }
}

// MLP 64->128->64->32->10 + graph-mean accumulation
__global__ void __launch_bounds__(256) k_mlp(
    const float* __restrict__ p_in, const int* __restrict__ gid,
    const float* __restrict__ fW1, const float* __restrict__ fb1,
    const float* __restrict__ fW2, const float* __restrict__ fb2,
    const float* __restrict__ fW3, const float* __restrict__ fb3,
    const float* __restrict__ fW4, const float* __restrict__ fb4,
    const float* __restrict__ inv_counts, float* __restrict__ out) {
  int i = blockIdx.x * blockDim.x + threadIdx.x;
  if (i >= NN) return;
  float p[64];
#pragma unroll
  for (int k = 0; k < 64; k += 4) {
    float4 v = *reinterpret_cast<const float4*>(p_in + (size_t)i * 64 + k);
    p[k] = v.x; p[k + 1] = v.y; p[k + 2] = v.z; p[k + 3] = v.w;
  }
  // fc1: 64 -> 128, relu
  float q[128];
#pragma unroll
  for (int j = 0; j < 128; ++j) {
    float a = fb1[j];
#pragma unroll
    for (int k = 0; k < 64; ++k) a = fmaf(p[k], fW1[k * 128 + j], a);
    q[j] = fmaxf(a, 0.f);
  }
  // fc2: 128 -> 64, relu
  float r[64];
#pragma unroll
  for (int j = 0; j < 64; ++j) {
    float a = fb2[j];
#pragma unroll
    for (int k = 0; k < 128; ++k) a = fmaf(q[k], fW2[k * 64 + j], a);
    r[j] = fmaxf(a, 0.f);
  }
  // fc3: 64 -> 32, relu
  float s[32];
#pragma unroll
  for (int j = 0; j < 32; ++j) {
    float a = fb3[j];
#pragma unroll
    for (int k = 0; k < 64; ++k) a = fmaf(r[k], fW3[k * 32 + j], a);
    s[j] = fmaxf(a, 0.f);
  }
  // fc4: 32 -> 10 + graph mean
  int g = gid[i];
  float ic = inv_counts[g];
#pragma unroll
  for (int j = 0; j < 10; ++j) {
    float a = fb4[j];
#pragma unroll
    for (int k = 0; k < 32; ++k) a = fmaf(s[k], fW4[k * 10 + j], a);
    atomicAdd(&out[g * 10 + j], a * ic);
  }
}

extern "C" void kernel_launch(void* const* d_in, const int* in_sizes, int n_in,
                              void* d_out, int out_size, void* d_ws, size_t ws_size,
                              hipStream_t stream) {
  const int* src = (const int*)d_in[0];
  const int* dst = (const int*)d_in[1];
  const int* gid = (const int*)d_in[2];
  const float* n_feat = (const float*)d_in[3];
  const float* W1 = (const float*)d_in[4];
  const float* b1 = (const float*)d_in[5];
  const float* W2 = (const float*)d_in[6];
  const float* b2 = (const float*)d_in[7];
  const float* W3 = (const float*)d_in[8];
  const float* b3 = (const float*)d_in[9];
  const float* fW1 = (const float*)d_in[10];
  const float* fb1 = (const float*)d_in[11];
  const float* fW2 = (const float*)d_in[12];
  const float* fb2 = (const float*)d_in[13];
  const float* fW3 = (const float*)d_in[14];
  const float* fb3 = (const float*)d_in[15];
  const float* fW4 = (const float*)d_in[16];
  const float* fb4 = (const float*)d_in[17];
  float* out = (float*)d_out;

  float* ws = (float*)d_ws;
  float* norm_out = ws;                    // NN
  float* norm_in = ws + NN;                // NN
  float* counts = ws + 2 * NN;             // 256
  float* agg = ws + 2 * NN + 256;          // 32*NN
  float* buf = agg + (size_t)32 * NN;      // 64*NN (xs0/xs1/xs2/p)

  hipMemsetAsync(norm_out, 0, (2 * NN + 256) * sizeof(float), stream);
  hipMemsetAsync(out, 0, (size_t)out_size * sizeof(float), stream);

  k_degree<<<(NE + 255) / 256, 256, 0, stream>>>(src, dst, norm_out, norm_in);
  k_norm_scale<<<(NN + 255) / 256, 256, 0, stream>>>(n_feat, gid, norm_out, norm_in, counts, buf);
  k_invcounts<<<1, 256, 0, stream>>>(counts);

  // layer 1: aggregate at d=8, then 8->16 relu
  hipMemsetAsync(agg, 0, (size_t)NN * 8 * sizeof(float), stream);
  k_scatter<8><<<(NE * 2 + 255) / 256, 256, 0, stream>>>(buf, src, dst, agg);
  k_layer<8, 16><<<(NN + 255) / 256, 256, 0, stream>>>(agg, norm_in, norm_out, W1, b1, buf);

  // layer 2: aggregate at d=16, then 16->32 relu
  hipMemsetAsync(agg, 0, (size_t)NN * 16 * sizeof(float), stream);
  k_scatter<16><<<(NE * 4 + 255) / 256, 256, 0, stream>>>(buf, src, dst, agg);
  k_layer<16, 32><<<(NN + 255) / 256, 256, 0, stream>>>(agg, norm_in, norm_out, W2, b2, buf);

  // layer 3: aggregate at d=32, then 32->128 + maxpool -> p[N,64]
  hipMemsetAsync(agg, 0, (size_t)NN * 32 * sizeof(float), stream);
  k_scatter<32><<<(NE * 8 + 255) / 256, 256, 0, stream>>>(buf, src, dst, agg);
  k_tail_a<<<(NN + 255) / 256, 256, 0, stream>>>(agg, norm_in, W3, b3, buf);

  // MLP + graph mean
  k_mlp<<<(NN + 255) / 256, 256, 0, stream>>>(buf, gid, fW1, fb1, fW2, fb2, fW3, fb3,
                                              fW4, fb4, counts, out);
}